// Round 6
// baseline (6050.460 us; speedup 1.0000x reference)
//
#include <hip/hip_runtime.h>
#include <hip/hip_bf16.h>
#include <cstdint>
#include <cstddef>

// ---------------------------------------------------------------------------
// SelfAttention (B=2, S=4096, H=2048, fp32 in/out), fp16 MFMA internally.
// Round 6: occupancy fix. 256x256 tile, BK=32, LDS 64KB (2x(16+16)KB dbuf)
// -> 2 blocks/CU (__launch_bounds__(512,4)). One phase per K-tile:
//   [stage next tile: 4 gld_lds] [12 ds_reads] [32 MFMA] [vmcnt(0)] [barrier]
// Cross-block co-scheduling (m114) absorbs the sync stalls a single resident
// block exposes (rounds 2-5 all ~21% occupancy, 37-42% MfmaUtil).
// Swizzle (64B rows): read col byte = (kq ^ ((fr>>1)&3))<<4  (<=2-way, free);
// staging keeps LDS linear and pre-permutes the GLOBAL source column with the
// same involution (both-sides rule): sc = ((lane&3)^((lane>>3)&3))<<3 halfs.
// + XCD-aware block swizzle (T1), bijective since all grids %8 == 0.
// ---------------------------------------------------------------------------

typedef _Float16 half8 __attribute__((ext_vector_type(8)));
typedef _Float16 half4 __attribute__((ext_vector_type(4)));
typedef float    f32x4 __attribute__((ext_vector_type(4)));

__device__ __forceinline__ void gld_lds16(const void* g, void* l) {
  __builtin_amdgcn_global_load_lds(
      (const __attribute__((address_space(1))) unsigned int*)g,
      (__attribute__((address_space(3))) unsigned int*)l, 16, 0, 0);
}

#define FENCE()  asm volatile("" ::: "memory")
#define VMC(n)   asm volatile("s_waitcnt vmcnt(" #n ")" ::: "memory")
#define SBARF()  do { __builtin_amdgcn_s_barrier(); FENCE(); } while (0)
#define PRIO1()  __builtin_amdgcn_s_setprio(1)
#define PRIO0()  __builtin_amdgcn_s_setprio(0)

// stage one full K-tile (A 256x32 + B 256x32 halfs) into buf b: 4 gld_lds/wave
#define STAGE(b, kOff) do {                                                  \
  const _Float16* _a = Asrc + (kOff);                                        \
  const _Float16* _b = Bsrc + (kOff);                                        \
  gld_lds16(_a,         ldsA + (b)*16384 + wvo);                             \
  gld_lds16(_a + lda16, ldsA + (b)*16384 + wvo + 1024);                      \
  gld_lds16(_b,         ldsB + (b)*16384 + wvo);                             \
  gld_lds16(_b + ldb16, ldsB + (b)*16384 + wvo + 1024);                      \
} while (0)

// one K-tile: optional next-tile stage, 12 frag reads, 32 MFMA, fence pair
#define TILE32(b, kOff, DO_STAGE) do {                                       \
  if (DO_STAGE) STAGE((b)^1, kOff);                                          \
  half8 af[8], bf[4];                                                        \
  _Pragma("unroll") for (int mi = 0; mi < 8; ++mi)                           \
    af[mi] = *(const half8*)(ldsA + (b)*16384 + wr*8192 + mi*1024 + vA);     \
  _Pragma("unroll") for (int ni = 0; ni < 4; ++ni)                           \
    bf[ni] = *(const half8*)(ldsB + (b)*16384 + wc*4096 + ni*1024 + vB);     \
  PRIO1();                                                                   \
  _Pragma("unroll") for (int mi = 0; mi < 8; ++mi)                           \
  _Pragma("unroll") for (int ni = 0; ni < 4; ++ni)                           \
    acc[mi][ni] = __builtin_amdgcn_mfma_f32_16x16x32_f16(                    \
        af[mi], bf[ni], acc[mi][ni], 0, 0, 0);                               \
  PRIO0();                                                                   \
  VMC(0);                                                                    \
  SBARF();                                                                   \
} while (0)

// MODE 0: fp32 row-major out, no bias   (scores, final out)
// MODE 1: fp16 row-major out + bias     (Q, K projections)
// MODE 2: fp16 TRANSPOSED out + bias    (V projection -> Vt[col*ldo + row])
template <int MODE>
__global__ __launch_bounds__(512, 4) void gemm256(
    const _Float16* __restrict__ A, int lda,
    const _Float16* __restrict__ B, int ldb,
    const float* __restrict__ bias,
    void* __restrict__ out, int ldo, int K,
    size_t sA, size_t sB, size_t sO)
{
  __shared__ __attribute__((aligned(128))) char lds[65536];
  char* ldsA = (char*)lds;            // buf b at b*16384
  char* ldsB = (char*)lds + 32768;    // buf b at b*16384

  const int tid  = threadIdx.x;
  const int wv   = tid >> 6;
  const int lane = tid & 63;
  const int wr = wv >> 2;             // wave row (M half, 128 rows)
  const int wc = wv & 3;              // wave col (64 cols)

  // XCD-aware block swizzle (bijective: nwg % 8 == 0 for all grids used)
  const int gx  = gridDim.x;
  const int lin = blockIdx.x + gx * blockIdx.y;
  const int q8  = (gx * gridDim.y) >> 3;
  const int wsw = (lin & 7) * q8 + (lin >> 3);
  const int bm  = (wsw % gx) * 256;
  const int bn  = (wsw / gx) * 256;
  A += (size_t)blockIdx.z * sA;
  B += (size_t)blockIdx.z * sB;

  // fragment-read indexing: row fr (64B rows), col slot kq swizzled by row
  const int fr = lane & 15;
  const int kq = lane >> 4;
  const int vcol = (kq ^ ((fr >> 1) & 3)) << 4;
  const int vA = fr * 64 + vcol;
  const int vB = fr * 64 + vcol;
  // staging indexing: lane covers row lane>>2, 16B slot (lane&3), source
  // column pre-permuted by the same involution (slot ^ ((row>>1)&3))
  const int rl = lane >> 2;
  const int sc = (((lane & 3) ^ ((lane >> 3) & 3)) << 3);

  const _Float16* Asrc = A + (size_t)(bm + wv * 32 + rl) * lda + sc;
  const _Float16* Bsrc = B + (size_t)(bn + wv * 32 + rl) * ldb + sc;
  const size_t lda16 = (size_t)lda * 16, ldb16 = (size_t)ldb * 16;
  const int wvo = wv * 2048;

  f32x4 acc[8][4];
  const f32x4 zf = {0.f, 0.f, 0.f, 0.f};
#pragma unroll
  for (int mi = 0; mi < 8; ++mi)
#pragma unroll
    for (int ni = 0; ni < 4; ++ni) acc[mi][ni] = zf;

  const int NT = K >> 5;        // K-tiles of 32 (64 or 128 here, even)
  const int NI = NT >> 1;

  // prologue: stage tile 0 into buf0, fence
  STAGE(0, 0);
  VMC(0);
  SBARF();

  size_t kOff = 32;
  for (int it = 0; it < NI; ++it) {
    TILE32(0, kOff, 1);               kOff += 32;   // read buf0, stage->buf1
    TILE32(1, kOff, (it != NI - 1));  kOff += 32;   // read buf1, stage->buf0
  }

  // epilogue. C/D frag: col = lane&15, rows = (lane>>4)*4 + j
#pragma unroll
  for (int mi = 0; mi < 8; ++mi) {
#pragma unroll
    for (int ni = 0; ni < 4; ++ni) {
      const int col  = bn + wc * 64 + ni * 16 + fr;
      const int row0 = bm + wr * 128 + mi * 16 + kq * 4;
      const f32x4 a = acc[mi][ni];
      if constexpr (MODE == 0) {
        float* O = (float*)out + (size_t)blockIdx.z * sO;
#pragma unroll
        for (int j = 0; j < 4; ++j) O[(size_t)(row0 + j) * ldo + col] = a[j];
      } else if constexpr (MODE == 1) {
        _Float16* O = (_Float16*)out;
        const float bb = bias[col];
#pragma unroll
        for (int j = 0; j < 4; ++j)
          O[(size_t)(row0 + j) * ldo + col] = (_Float16)(a[j] + bb);
      } else {
        _Float16* O = (_Float16*)out;
        const float bb = bias[col];
        half4 h;
#pragma unroll
        for (int j = 0; j < 4; ++j) h[j] = (_Float16)(a[j] + bb);
        *(half4*)(O + (size_t)col * ldo + row0) = h;
      }
    }
  }
}

__device__ __forceinline__ float wave_max_f(float v) {
#pragma unroll
  for (int o = 32; o; o >>= 1) v = fmaxf(v, __shfl_xor(v, o));
  return v;
}
__device__ __forceinline__ float wave_sum_f(float v) {
#pragma unroll
  for (int o = 32; o; o >>= 1) v += __shfl_xor(v, o);
  return v;
}

// one 256-thread block per row of 4096 fp32 scores -> fp16 probabilities
__global__ __launch_bounds__(256) void softmax_rows(
    const float* __restrict__ S, _Float16* __restrict__ P)
{
  __shared__ float rmax[4], rsum[4];
  const int tid = threadIdx.x;
  const float* s = S + (size_t)blockIdx.x * 4096;
  _Float16*    p = P + (size_t)blockIdx.x * 4096;

  f32x4 v[4];
  float m = -3.0e38f;
#pragma unroll
  for (int i = 0; i < 4; ++i) {
    v[i] = ((const f32x4*)s)[i * 256 + tid];
#pragma unroll
    for (int j = 0; j < 4; ++j) m = fmaxf(m, v[i][j]);
  }
  m = wave_max_f(m);
  if ((tid & 63) == 0) rmax[tid >> 6] = m;
  __syncthreads();
  m = fmaxf(fmaxf(rmax[0], rmax[1]), fmaxf(rmax[2], rmax[3]));

  float e[16];
  float sum = 0.f;
#pragma unroll
  for (int i = 0; i < 4; ++i)
#pragma unroll
    for (int j = 0; j < 4; ++j) {
      const float t = __expf(v[i][j] - m);
      e[i * 4 + j] = t;
      sum += t;
    }
  sum = wave_sum_f(sum);
  if ((tid & 63) == 0) rsum[tid >> 6] = sum;
  __syncthreads();
  sum = rsum[0] + rsum[1] + rsum[2] + rsum[3];
  const float inv = 1.0f / sum;

#pragma unroll
  for (int i = 0; i < 4; ++i) {
    half4 h;
#pragma unroll
    for (int j = 0; j < 4; ++j) h[j] = (_Float16)(e[i * 4 + j] * inv);
    ((half4*)p)[i * 256 + tid] = h;
  }
}

__global__ __launch_bounds__(256) void cvt_f32_f16(
    const float* __restrict__ in, _Float16* __restrict__ out, int n4)
{
  const int stride = gridDim.x * 256;
  for (int idx = blockIdx.x * 256 + threadIdx.x; idx < n4; idx += stride) {
    const f32x4 x = ((const f32x4*)in)[idx];
    half4 h;
#pragma unroll
    for (int j = 0; j < 4; ++j) h[j] = (_Float16)x[j];
    ((half4*)out)[idx] = h;
  }
}

extern "C" void kernel_launch(void* const* d_in, const int* in_sizes, int n_in,
                              void* d_out, int out_size, void* d_ws, size_t ws_size,
                              hipStream_t stream)
{
  const float* X  = (const float*)d_in[0];
  const float* Wq = (const float*)d_in[1];
  const float* bq = (const float*)d_in[2];
  const float* Wk = (const float*)d_in[3];
  const float* bk = (const float*)d_in[4];
  const float* Wv = (const float*)d_in[5];
  const float* bv = (const float*)d_in[6];
  float* out = (float*)d_out;

  const size_t NX = (size_t)2 * 4096 * 2048;  // 16,777,216
  const size_t NW = (size_t)2048 * 2048;      //  4,194,304
  const size_t NS = (size_t)2 * 4096 * 4096;  // 33,554,432

  // Workspace layout (lifetime-aliased, total ~235 MB)
  char* w = (char*)d_ws;
  float*    Ssc = (float*)w;
  _Float16* Xh  = (_Float16*)w;
  _Float16* Wqh = (_Float16*)(w + NX * 2);
  _Float16* Wkh = (_Float16*)(w + NX * 2 + NW * 2);
  _Float16* Wvh = (_Float16*)(w + NX * 2 + 2 * NW * 2);
  _Float16* Q   = (_Float16*)(w + NS * 4);
  _Float16* Kp  = (_Float16*)(w + NS * 4 + NX * 2);
  _Float16* P   = (_Float16*)(w + NS * 4);            // aliases Q+Kp
  _Float16* Vt  = (_Float16*)(w + NS * 4 + 2 * NX * 2);

  // 1) fp32 -> fp16 conversions
  cvt_f32_f16<<<2048, 256, 0, stream>>>(X,  Xh,  (int)(NX / 4));
  cvt_f32_f16<<<512,  256, 0, stream>>>(Wq, Wqh, (int)(NW / 4));
  cvt_f32_f16<<<512,  256, 0, stream>>>(Wk, Wkh, (int)(NW / 4));
  cvt_f32_f16<<<512,  256, 0, stream>>>(Wv, Wvh, (int)(NW / 4));

  const dim3 blk(512);
  // 2) projections: [8192,2048] = Xh @ W^T + b
  gemm256<1><<<dim3(32, 8, 1), blk, 0, stream>>>(Xh, 2048, Wqh, 2048, bq,
                                                 Q, 2048, 2048, 0, 0, 0);
  gemm256<1><<<dim3(32, 8, 1), blk, 0, stream>>>(Xh, 2048, Wkh, 2048, bk,
                                                 Kp, 2048, 2048, 0, 0, 0);
  gemm256<2><<<dim3(32, 8, 1), blk, 0, stream>>>(Xh, 2048, Wvh, 2048, bv,
                                                 Vt, 8192, 2048, 0, 0, 0);
  // 3) scores: per batch, S = Q K^T (fp32)
  gemm256<0><<<dim3(16, 16, 2), blk, 0, stream>>>(
      Q, 2048, Kp, 2048, nullptr, Ssc, 4096, 2048,
      (size_t)4096 * 2048, (size_t)4096 * 2048, (size_t)4096 * 4096);
  // 4) row softmax -> fp16 probs
  softmax_rows<<<8192, 256, 0, stream>>>(Ssc, P);
  // 5) out: per batch, [4096,2048] = P @ Vt^T
  gemm256<0><<<dim3(16, 8, 2), blk, 0, stream>>>(
      P, 4096, Vt, 8192, nullptr, out, 2048, 4096,
      (size_t)4096 * 4096, (size_t)4096, (size_t)4096 * 2048);
}

// Round 8
// 494.324 us; speedup vs baseline: 12.2399x; 12.2399x over previous
//
#include <hip/hip_runtime.h>
#include <hip/hip_bf16.h>
#include <cstdint>
#include <cstddef>

// ---------------------------------------------------------------------------
// SelfAttention (B=2, S=4096, H=2048, fp32 in/out), fp16 MFMA internally.
// Round 8: round-3 structure (verified correct) with m201's uniform stage
// interleave: exactly ONE half-tile staged per phase, placed per region
// lifetimes (A regions are ds_read at ph1 AND ph3; B regions at ph1 AND ph2
// — round 7's bug was staging an A region at ph2):
//   ph1: buf1.A0(t+1)  ph2: buf1.A1(t+1)   [buf1.A free after prev ph7]
//   ph3: buf0.B0(t+2)  ph4: buf0.B1(t+2)   [buf0.B free after ph2]
//   ph5: buf0.A0(t+2)  ph6: buf0.A1(t+2)   [buf0.A free after ph3]
//   ph7: buf1.B0(t+3)  ph8: buf1.B1(t+3)   [buf1.B free after ph6]
// FIFO ledger: VMC(4)@ph4 drains ALL t+1 (12->4); VMC(4)@ph8 drains ALL t+2.
// Last iter: ph1/ph2 stages kept (t+1=NT-1 needed), ph3-8 skipped, VMC(0).
// Both B halves kept in registers (24 ds_reads/K-tile, no ph4/ph8 re-read).
// ---------------------------------------------------------------------------

typedef _Float16 half8 __attribute__((ext_vector_type(8)));
typedef _Float16 half4 __attribute__((ext_vector_type(4)));
typedef float    f32x4 __attribute__((ext_vector_type(4)));

__device__ __forceinline__ void gld_lds16(const void* g, void* l) {
  __builtin_amdgcn_global_load_lds(
      (const __attribute__((address_space(1))) unsigned int*)g,
      (__attribute__((address_space(3))) unsigned int*)l, 16, 0, 0);
}

#define FENCE()  asm volatile("" ::: "memory")
#define LGKM(n)  asm volatile("s_waitcnt lgkmcnt(" #n ")" ::: "memory")
#define VMC(n)   asm volatile("s_waitcnt vmcnt(" #n ")" ::: "memory")
#define SBAR()   do { __builtin_amdgcn_s_barrier(); FENCE(); } while (0)
#define SCHED0() __builtin_amdgcn_sched_barrier(0)
#define PRIO1()  __builtin_amdgcn_s_setprio(1)
#define PRIO0()  __builtin_amdgcn_s_setprio(0)

// A subtile (m-half MH) from buffer RB into af: 8 x ds_read_b128 (C++ reads)
#define LOAD_A(dst, RB, MH) do {                                            \
  const char* _p = ldsA + ((RB)*2 + wr) * 16384 + fr * 128;                 \
  _Pragma("unroll") for (int mi = 0; mi < 4; ++mi) {                        \
    dst[mi][0] = *(const half8*)(_p + ((MH)*4 + mi) * 2048 + cS0);          \
    dst[mi][1] = *(const half8*)(_p + ((MH)*4 + mi) * 2048 + cS1);          \
  }                                                                         \
} while (0)

// B subtile (n-half NH) from buffer RB into dst: 4 x ds_read_b128
#define LOAD_B(dst, RB, NH) do {                                            \
  const char* _p = ldsB + ((RB)*2 + (wc >> 1)) * 16384 +                    \
                   ((wc & 1) * 64 + fr) * 128;                              \
  _Pragma("unroll") for (int ni = 0; ni < 2; ++ni) {                        \
    dst[ni][0] = *(const half8*)(_p + ((NH)*2 + ni) * 2048 + cS0);          \
    dst[ni][1] = *(const half8*)(_p + ((NH)*2 + ni) * 2048 + cS1);          \
  }                                                                         \
} while (0)

// one C-quadrant x K=64: 16 MFMA
#define MFMA_Q(AF, BF, MH, NH)                                              \
  _Pragma("unroll") for (int mi = 0; mi < 4; ++mi)                          \
  _Pragma("unroll") for (int ni = 0; ni < 2; ++ni) {                        \
    f32x4& _c = acc[(MH)*4 + mi][(NH)*2 + ni];                              \
    _c = __builtin_amdgcn_mfma_f32_16x16x32_f16(AF[mi][0], BF[ni][0], _c, 0, 0, 0); \
    _c = __builtin_amdgcn_mfma_f32_16x16x32_f16(AF[mi][1], BF[ni][1], _c, 0, 0, 0); \
  }

// stage one 128x64 half-tile (16KB): 2 x global_load_lds(16B) per wave.
// LDS linear; global source column pre-swizzled (involution, both-sides).
#define STAGE_A(bsel, h, kof)                                               \
  {                                                                         \
    const _Float16* _s = Abase + (size_t)((h) * 128) * lda + (kof);         \
    char* _d = ldsA + ((bsel)*2 + (h)) * 16384 + wvd;                       \
    gld_lds16(_s, _d);                                                      \
    gld_lds16(_s + lda8, _d + 1024);                                        \
  }
#define STAGE_B(bsel, h, kof)                                               \
  {                                                                         \
    const _Float16* _s = Bbase + (size_t)((h) * 128) * ldb + (kof);         \
    char* _d = ldsB + ((bsel)*2 + (h)) * 16384 + wvd;                       \
    gld_lds16(_s, _d);                                                      \
    gld_lds16(_s + ldb8, _d + 1024);                                        \
  }

// MODE 0: fp32 row-major out, no bias   (scores, final out)
// MODE 1: fp16 row-major out + bias     (Q, K projections)
// MODE 2: fp16 TRANSPOSED out + bias    (V projection -> Vt[col*ldo + row])
template <int MODE>
__global__ __launch_bounds__(512) void gemm256(
    const _Float16* __restrict__ A, int lda,
    const _Float16* __restrict__ B, int ldb,
    const float* __restrict__ bias,
    void* __restrict__ out, int ldo, int K,
    size_t sA, size_t sB, size_t sO)
{
  __shared__ __attribute__((aligned(128))) char lds[131072];
  char* ldsA = (char*)lds;       // region: (bsel*2+half)*16384
  char* ldsB = (char*)lds + 65536;

  const int tid  = threadIdx.x;
  const int wv   = tid >> 6;
  const int lane = tid & 63;
  const int wr = wv >> 2;           // wave row (M half, 128 rows)
  const int wc = wv & 3;            // wave col (64 cols)
  const int bm = blockIdx.x * 256;
  const int bn = blockIdx.y * 256;
  A += (size_t)blockIdx.z * sA;
  B += (size_t)blockIdx.z * sB;

  // fragment-read indexing (swizzle verified rounds 2-3)
  const int fr = lane & 15;
  const int kq = lane >> 4;
  const int sx = (fr & 7) << 4;
  const int cS0 = (kq * 16) ^ sx;
  const int cS1 = (64 + kq * 16) ^ sx;
  // staging indexing (verified rounds 2-3)
  const int lr  = lane >> 3;
  const int sc8 = ((lane & 7) ^ (lr & 7)) << 3;

  const _Float16* Abase = A + (size_t)(bm + wv * 16 + lr) * lda + sc8;
  const _Float16* Bbase = B + (size_t)(bn + wv * 16 + lr) * ldb + sc8;
  const size_t lda8 = (size_t)lda * 8, ldb8 = (size_t)ldb * 8;
  const int wvd = wv * 2048;

  f32x4 acc[8][4];
  const f32x4 zf = {0.f, 0.f, 0.f, 0.f};
#pragma unroll
  for (int mi = 0; mi < 8; ++mi)
#pragma unroll
    for (int ni = 0; ni < 4; ++ni) acc[mi][ni] = zf;

  half8 af[4][2], bf0[2][2], bf1[2][2];

  const int NT = K >> 6;        // 32 or 64 (even, >= 4)
  const int NI = NT >> 1;

  // prologue: t0 full (8 loads) + t1.{B0,B1} (4 loads, = steady prev-ph7/8);
  // VMC(4) drains t0 only.
  STAGE_A(0, 0, 0); STAGE_A(0, 1, 0); STAGE_B(0, 0, 0); STAGE_B(0, 1, 0);
  STAGE_B(1, 0, 64); STAGE_B(1, 1, 64);
  VMC(4);
  SBAR();

  for (int it = 0; it < NI; ++it) {
    const bool more = (it < NI - 1);
    const size_t t1k = (size_t)(2 * it + 1) * 64;   // buf1 tile (this group)
    const size_t t2k = t1k + 64;                    // buf0 next tile
    const size_t t3k = t1k + 128;                   // buf1 next tile

    // ===== group 1: buf0, tile 2it =====
    // ph1: reads A(MH0)+B(NH0) (12); stage buf1.A0(t+1) [free since prev ph7]
    LOAD_A(af, 0, 0); LOAD_B(bf0, 0, 0);
    STAGE_A(1, 0, t1k);
    LGKM(8);
    SBAR(); LGKM(0); SCHED0();
    PRIO1(); MFMA_Q(af, bf0, 0, 0); PRIO0();
    SBAR();
    // ph2: reads B(NH1) (4); stage buf1.A1(t+1)
    LOAD_B(bf1, 0, 1);
    STAGE_A(1, 1, t1k);
    SBAR(); LGKM(0); SCHED0();
    PRIO1(); MFMA_Q(af, bf1, 0, 1); PRIO0();
    SBAR();
    // ph3: reads A(MH1) (8); stage buf0.B0(t+2) [buf0.B free after ph2]
    LOAD_A(af, 0, 1);
    if (more) STAGE_B(0, 0, t2k);
    SBAR(); LGKM(0); SCHED0();
    PRIO1(); MFMA_Q(af, bf1, 1, 1); PRIO0();
    SBAR();
    // ph4: no reads; stage buf0.B1(t+2); VMC drains ALL t+1 stages
    if (more) STAGE_B(0, 1, t2k);
    SBAR(); SCHED0();
    PRIO1(); MFMA_Q(af, bf0, 1, 0); PRIO0();
    if (more) { VMC(4); } else { VMC(0); }
    SBAR();

    // ===== group 2: buf1, tile 2it+1 =====
    // ph5: reads A(MH0)+B(NH0) (12); stage buf0.A0(t+2) [buf0.A free after ph3]
    LOAD_A(af, 1, 0); LOAD_B(bf0, 1, 0);
    if (more) STAGE_A(0, 0, t2k);
    LGKM(8);
    SBAR(); LGKM(0); SCHED0();
    PRIO1(); MFMA_Q(af, bf0, 0, 0); PRIO0();
    SBAR();
    // ph6: reads B(NH1) (4); stage buf0.A1(t+2)
    LOAD_B(bf1, 1, 1);
    if (more) STAGE_A(0, 1, t2k);
    SBAR(); LGKM(0); SCHED0();
    PRIO1(); MFMA_Q(af, bf1, 0, 1); PRIO0();
    SBAR();
    // ph7: reads A(MH1) (8); stage buf1.B0(t+3) [buf1.B free after ph6]
    LOAD_A(af, 1, 1);
    if (more) STAGE_B(1, 0, t3k);
    SBAR(); LGKM(0); SCHED0();
    PRIO1(); MFMA_Q(af, bf1, 1, 1); PRIO0();
    SBAR();
    // ph8: no reads; stage buf1.B1(t+3); VMC drains ALL t+2 stages
    if (more) STAGE_B(1, 1, t3k);
    SBAR(); SCHED0();
    PRIO1(); MFMA_Q(af, bf0, 1, 0); PRIO0();
    if (more) { VMC(4); } else { VMC(0); }
    SBAR();
  }

  // epilogue. C/D frag: col = lane&15, rows = (lane>>4)*4 + j
#pragma unroll
  for (int mi = 0; mi < 8; ++mi) {
#pragma unroll
    for (int ni = 0; ni < 4; ++ni) {
      const int col  = bn + wc * 64 + ni * 16 + fr;
      const int row0 = bm + wr * 128 + mi * 16 + kq * 4;
      const f32x4 a = acc[mi][ni];
      if constexpr (MODE == 0) {
        float* O = (float*)out + (size_t)blockIdx.z * sO;
#pragma unroll
        for (int j = 0; j < 4; ++j) O[(size_t)(row0 + j) * ldo + col] = a[j];
      } else if constexpr (MODE == 1) {
        _Float16* O = (_Float16*)out;
        const float bb = bias[col];
#pragma unroll
        for (int j = 0; j < 4; ++j)
          O[(size_t)(row0 + j) * ldo + col] = (_Float16)(a[j] + bb);
      } else {
        _Float16* O = (_Float16*)out;
        const float bb = bias[col];
        half4 h;
#pragma unroll
        for (int j = 0; j < 4; ++j) h[j] = (_Float16)(a[j] + bb);
        *(half4*)(O + (size_t)col * ldo + row0) = h;
      }
    }
  }
}

__device__ __forceinline__ float wave_max_f(float v) {
#pragma unroll
  for (int o = 32; o; o >>= 1) v = fmaxf(v, __shfl_xor(v, o));
  return v;
}
__device__ __forceinline__ float wave_sum_f(float v) {
#pragma unroll
  for (int o = 32; o; o >>= 1) v += __shfl_xor(v, o);
  return v;
}

// one 256-thread block per row of 4096 fp32 scores -> fp16 probabilities
__global__ __launch_bounds__(256) void softmax_rows(
    const float* __restrict__ S, _Float16* __restrict__ P)
{
  __shared__ float rmax[4], rsum[4];
  const int tid = threadIdx.x;
  const float* s = S + (size_t)blockIdx.x * 4096;
  _Float16*    p = P + (size_t)blockIdx.x * 4096;

  f32x4 v[4];
  float m = -3.0e38f;
#pragma unroll
  for (int i = 0; i < 4; ++i) {
    v[i] = ((const f32x4*)s)[i * 256 + tid];
#pragma unroll
    for (int j = 0; j < 4; ++j) m = fmaxf(m, v[i][j]);
  }
  m = wave_max_f(m);
  if ((tid & 63) == 0) rmax[tid >> 6] = m;
  __syncthreads();
  m = fmaxf(fmaxf(rmax[0], rmax[1]), fmaxf(rmax[2], rmax[3]));

  float e[16];
  float sum = 0.f;
#pragma unroll
  for (int i = 0; i < 4; ++i)
#pragma unroll
    for (int j = 0; j < 4; ++j) {
      const float t = __expf(v[i][j] - m);
      e[i * 4 + j] = t;
      sum += t;
    }
  sum = wave_sum_f(sum);
  if ((tid & 63) == 0) rsum[tid >> 6] = sum;
  __syncthreads();
  sum = rsum[0] + rsum[1] + rsum[2] + rsum[3];
  const float inv = 1.0f / sum;

#pragma unroll
  for (int i = 0; i < 4; ++i) {
    half4 h;
#pragma unroll
    for (int j = 0; j < 4; ++j) h[j] = (_Float16)(e[i * 4 + j] * inv);
    ((half4*)p)[i * 256 + tid] = h;
  }
}

__global__ __launch_bounds__(256) void cvt_f32_f16(
    const float* __restrict__ in, _Float16* __restrict__ out, int n4)
{
  const int stride = gridDim.x * 256;
  for (int idx = blockIdx.x * 256 + threadIdx.x; idx < n4; idx += stride) {
    const f32x4 x = ((const f32x4*)in)[idx];
    half4 h;
#pragma unroll
    for (int j = 0; j < 4; ++j) h[j] = (_Float16)x[j];
    ((half4*)out)[idx] = h;
  }
}

extern "C" void kernel_launch(void* const* d_in, const int* in_sizes, int n_in,
                              void* d_out, int out_size, void* d_ws, size_t ws_size,
                              hipStream_t stream)
{
  const float* X  = (const float*)d_in[0];
  const float* Wq = (const float*)d_in[1];
  const float* bq = (const float*)d_in[2];
  const float* Wk = (const float*)d_in[3];
  const float* bk = (const float*)d_in[4];
  const float* Wv = (const float*)d_in[5];
  const float* bv = (const float*)d_in[6];
  float* out = (float*)d_out;

  const size_t NX = (size_t)2 * 4096 * 2048;  // 16,777,216
  const size_t NW = (size_t)2048 * 2048;      //  4,194,304
  const size_t NS = (size_t)2 * 4096 * 4096;  // 33,554,432

  // Workspace layout (lifetime-aliased, total ~235 MB)
  char* w = (char*)d_ws;
  float*    Ssc = (float*)w;
  _Float16* Xh  = (_Float16*)w;
  _Float16* Wqh = (_Float16*)(w + NX * 2);
  _Float16* Wkh = (_Float16*)(w + NX * 2 + NW * 2);
  _Float16* Wvh = (_Float16*)(w + NX * 2 + 2 * NW * 2);
  _Float16* Q   = (_Float16*)(w + NS * 4);
  _Float16* Kp  = (_Float16*)(w + NS * 4 + NX * 2);
  _Float16* P   = (_Float16*)(w + NS * 4);            // aliases Q+Kp
  _Float16* Vt  = (_Float16*)(w + NS * 4 + 2 * NX * 2);

  // 1) fp32 -> fp16 conversions
  cvt_f32_f16<<<2048, 256, 0, stream>>>(X,  Xh,  (int)(NX / 4));
  cvt_f32_f16<<<512,  256, 0, stream>>>(Wq, Wqh, (int)(NW / 4));
  cvt_f32_f16<<<512,  256, 0, stream>>>(Wk, Wkh, (int)(NW / 4));
  cvt_f32_f16<<<512,  256, 0, stream>>>(Wv, Wvh, (int)(NW / 4));

  const dim3 blk(512);
  // 2) projections: [8192,2048] = Xh @ W^T + b
  gemm256<1><<<dim3(32, 8, 1), blk, 0, stream>>>(Xh, 2048, Wqh, 2048, bq,
                                                 Q, 2048, 2048, 0, 0, 0);
  gemm256<1><<<dim3(32, 8, 1), blk, 0, stream>>>(Xh, 2048, Wkh, 2048, bk,
                                                 Kp, 2048, 2048, 0, 0, 0);
  gemm256<2><<<dim3(32, 8, 1), blk, 0, stream>>>(Xh, 2048, Wvh, 2048, bv,
                                                 Vt, 8192, 2048, 0, 0, 0);
  // 3) scores: per batch, S = Q K^T (fp32)
  gemm256<0><<<dim3(16, 16, 2), blk, 0, stream>>>(
      Q, 2048, Kp, 2048, nullptr, Ssc, 4096, 2048,
      (size_t)4096 * 2048, (size_t)4096 * 2048, (size_t)4096 * 4096);
  // 4) row softmax -> fp16 probs
  softmax_rows<<<8192, 256, 0, stream>>>(Ssc, P);
  // 5) out: per batch, [4096,2048] = P @ Vt^T
  gemm256<0><<<dim3(16, 8, 2), blk, 0, stream>>>(
      P, 4096, Vt, 8192, nullptr, out, 2048, 4096,
      (size_t)4096 * 4096, (size_t)4096, (size_t)4096 * 2048);
}

// Round 10
// 489.817 us; speedup vs baseline: 12.3525x; 1.0092x over previous
//
#include <hip/hip_runtime.h>
#include <hip/hip_bf16.h>
#include <cstdint>
#include <cstddef>

// ---------------------------------------------------------------------------
// SelfAttention (B=2, S=4096, H=2048, fp32 in/out), fp16 MFMA internally.
// Round 10: round-8 GEMM skeleton byte-identical (16x16x32, verified stable
// 3x at 141us/dispatch). Single change vs round 8: scores S stored fp16
// (QK^T MODE 3 + fp16 softmax I/O) — saves ~132 MB HBM traffic.
// Round 9's 32x32x16 port caused a post-timing race and is reverted.
// ---------------------------------------------------------------------------

typedef _Float16 half8 __attribute__((ext_vector_type(8)));
typedef _Float16 half4 __attribute__((ext_vector_type(4)));
typedef float    f32x4 __attribute__((ext_vector_type(4)));

__device__ __forceinline__ void gld_lds16(const void* g, void* l) {
  __builtin_amdgcn_global_load_lds(
      (const __attribute__((address_space(1))) unsigned int*)g,
      (__attribute__((address_space(3))) unsigned int*)l, 16, 0, 0);
}

#define FENCE()  asm volatile("" ::: "memory")
#define LGKM(n)  asm volatile("s_waitcnt lgkmcnt(" #n ")" ::: "memory")
#define VMC(n)   asm volatile("s_waitcnt vmcnt(" #n ")" ::: "memory")
#define SBAR()   do { __builtin_amdgcn_s_barrier(); FENCE(); } while (0)
#define SCHED0() __builtin_amdgcn_sched_barrier(0)
#define PRIO1()  __builtin_amdgcn_s_setprio(1)
#define PRIO0()  __builtin_amdgcn_s_setprio(0)

// A subtile (m-half MH) from buffer RB into af: 8 x ds_read_b128 (C++ reads)
#define LOAD_A(dst, RB, MH) do {                                            \
  const char* _p = ldsA + ((RB)*2 + wr) * 16384 + fr * 128;                 \
  _Pragma("unroll") for (int mi = 0; mi < 4; ++mi) {                        \
    dst[mi][0] = *(const half8*)(_p + ((MH)*4 + mi) * 2048 + cS0);          \
    dst[mi][1] = *(const half8*)(_p + ((MH)*4 + mi) * 2048 + cS1);          \
  }                                                                         \
} while (0)

// B subtile (n-half NH) from buffer RB into dst: 4 x ds_read_b128
#define LOAD_B(dst, RB, NH) do {                                            \
  const char* _p = ldsB + ((RB)*2 + (wc >> 1)) * 16384 +                    \
                   ((wc & 1) * 64 + fr) * 128;                              \
  _Pragma("unroll") for (int ni = 0; ni < 2; ++ni) {                        \
    dst[ni][0] = *(const half8*)(_p + ((NH)*2 + ni) * 2048 + cS0);          \
    dst[ni][1] = *(const half8*)(_p + ((NH)*2 + ni) * 2048 + cS1);          \
  }                                                                         \
} while (0)

// one C-quadrant x K=64: 16 MFMA
#define MFMA_Q(AF, BF, MH, NH)                                              \
  _Pragma("unroll") for (int mi = 0; mi < 4; ++mi)                          \
  _Pragma("unroll") for (int ni = 0; ni < 2; ++ni) {                        \
    f32x4& _c = acc[(MH)*4 + mi][(NH)*2 + ni];                              \
    _c = __builtin_amdgcn_mfma_f32_16x16x32_f16(AF[mi][0], BF[ni][0], _c, 0, 0, 0); \
    _c = __builtin_amdgcn_mfma_f32_16x16x32_f16(AF[mi][1], BF[ni][1], _c, 0, 0, 0); \
  }

// stage one 128x64 half-tile (16KB): 2 x global_load_lds(16B) per wave.
// LDS linear; global source column pre-swizzled (involution, both-sides).
#define STAGE_A(bsel, h, kof)                                               \
  {                                                                         \
    const _Float16* _s = Abase + (size_t)((h) * 128) * lda + (kof);         \
    char* _d = ldsA + ((bsel)*2 + (h)) * 16384 + wvd;                       \
    gld_lds16(_s, _d);                                                      \
    gld_lds16(_s + lda8, _d + 1024);                                        \
  }
#define STAGE_B(bsel, h, kof)                                               \
  {                                                                         \
    const _Float16* _s = Bbase + (size_t)((h) * 128) * ldb + (kof);         \
    char* _d = ldsB + ((bsel)*2 + (h)) * 16384 + wvd;                       \
    gld_lds16(_s, _d);                                                      \
    gld_lds16(_s + ldb8, _d + 1024);                                        \
  }

// MODE 0: fp32 row-major, no bias      (final out)
// MODE 1: fp16 row-major + bias        (Q, K projections)
// MODE 2: fp16 TRANSPOSED + bias       (V -> Vt[col*ldo + row])
// MODE 3: fp16 row-major, no bias      (scores S)
template <int MODE>
__global__ __launch_bounds__(512) void gemm256(
    const _Float16* __restrict__ A, int lda,
    const _Float16* __restrict__ B, int ldb,
    const float* __restrict__ bias,
    void* __restrict__ out, int ldo, int K,
    size_t sA, size_t sB, size_t sO)
{
  __shared__ __attribute__((aligned(128))) char lds[131072];
  char* ldsA = (char*)lds;       // region: (bsel*2+half)*16384
  char* ldsB = (char*)lds + 65536;

  const int tid  = threadIdx.x;
  const int wv   = tid >> 6;
  const int lane = tid & 63;
  const int wr = wv >> 2;           // wave row (M half, 128 rows)
  const int wc = wv & 3;            // wave col (64 cols)
  const int bm = blockIdx.x * 256;
  const int bn = blockIdx.y * 256;
  A += (size_t)blockIdx.z * sA;
  B += (size_t)blockIdx.z * sB;

  // fragment-read indexing (swizzle verified rounds 2-8)
  const int fr = lane & 15;
  const int kq = lane >> 4;
  const int sx = (fr & 7) << 4;
  const int cS0 = (kq * 16) ^ sx;
  const int cS1 = (64 + kq * 16) ^ sx;
  // staging indexing (verified rounds 2-8)
  const int lr  = lane >> 3;
  const int sc8 = ((lane & 7) ^ (lr & 7)) << 3;

  const _Float16* Abase = A + (size_t)(bm + wv * 16 + lr) * lda + sc8;
  const _Float16* Bbase = B + (size_t)(bn + wv * 16 + lr) * ldb + sc8;
  const size_t lda8 = (size_t)lda * 8, ldb8 = (size_t)ldb * 8;
  const int wvd = wv * 2048;

  f32x4 acc[8][4];
  const f32x4 zf = {0.f, 0.f, 0.f, 0.f};
#pragma unroll
  for (int mi = 0; mi < 8; ++mi)
#pragma unroll
    for (int ni = 0; ni < 4; ++ni) acc[mi][ni] = zf;

  half8 af[4][2], bf0[2][2], bf1[2][2];

  const int NT = K >> 6;        // 32 or 64 (even, >= 4)
  const int NI = NT >> 1;

  // prologue: t0 full (8 loads) + t1.{B0,B1} (4 loads); VMC(4) drains t0.
  STAGE_A(0, 0, 0); STAGE_A(0, 1, 0); STAGE_B(0, 0, 0); STAGE_B(0, 1, 0);
  STAGE_B(1, 0, 64); STAGE_B(1, 1, 64);
  VMC(4);
  SBAR();

  for (int it = 0; it < NI; ++it) {
    const bool more = (it < NI - 1);
    const size_t t1k = (size_t)(2 * it + 1) * 64;   // buf1 tile (this group)
    const size_t t2k = t1k + 64;                    // buf0 next tile
    const size_t t3k = t1k + 128;                   // buf1 next tile

    // ===== group 1: buf0, tile 2it =====
    // ph1: reads A(MH0)+B(NH0) (12); stage buf1.A0(t+1)
    LOAD_A(af, 0, 0); LOAD_B(bf0, 0, 0);
    STAGE_A(1, 0, t1k);
    LGKM(8);
    SBAR(); LGKM(0); SCHED0();
    PRIO1(); MFMA_Q(af, bf0, 0, 0); PRIO0();
    SBAR();
    // ph2: reads B(NH1) (4); stage buf1.A1(t+1)
    LOAD_B(bf1, 0, 1);
    STAGE_A(1, 1, t1k);
    SBAR(); LGKM(0); SCHED0();
    PRIO1(); MFMA_Q(af, bf1, 0, 1); PRIO0();
    SBAR();
    // ph3: reads A(MH1) (8); stage buf0.B0(t+2)
    LOAD_A(af, 0, 1);
    if (more) STAGE_B(0, 0, t2k);
    SBAR(); LGKM(0); SCHED0();
    PRIO1(); MFMA_Q(af, bf1, 1, 1); PRIO0();
    SBAR();
    // ph4: no reads; stage buf0.B1(t+2); VMC drains ALL t+1 stages
    if (more) STAGE_B(0, 1, t2k);
    SBAR(); SCHED0();
    PRIO1(); MFMA_Q(af, bf0, 1, 0); PRIO0();
    if (more) { VMC(4); } else { VMC(0); }
    SBAR();

    // ===== group 2: buf1, tile 2it+1 =====
    // ph5: reads A(MH0)+B(NH0) (12); stage buf0.A0(t+2)
    LOAD_A(af, 1, 0); LOAD_B(bf0, 1, 0);
    if (more) STAGE_A(0, 0, t2k);
    LGKM(8);
    SBAR(); LGKM(0); SCHED0();
    PRIO1(); MFMA_Q(af, bf0, 0, 0); PRIO0();
    SBAR();
    // ph6: reads B(NH1) (4); stage buf0.A1(t+2)
    LOAD_B(bf1, 1, 1);
    if (more) STAGE_A(0, 1, t2k);
    SBAR(); LGKM(0); SCHED0();
    PRIO1(); MFMA_Q(af, bf1, 0, 1); PRIO0();
    SBAR();
    // ph7: reads A(MH1) (8); stage buf1.B0(t+3)
    LOAD_A(af, 1, 1);
    if (more) STAGE_B(1, 0, t3k);
    SBAR(); LGKM(0); SCHED0();
    PRIO1(); MFMA_Q(af, bf1, 1, 1); PRIO0();
    SBAR();
    // ph8: no reads; stage buf1.B1(t+3); VMC drains ALL t+2 stages
    if (more) STAGE_B(1, 1, t3k);
    SBAR(); SCHED0();
    PRIO1(); MFMA_Q(af, bf0, 1, 0); PRIO0();
    if (more) { VMC(4); } else { VMC(0); }
    SBAR();
  }

  // epilogue. C/D frag: col = lane&15, rows = (lane>>4)*4 + j
#pragma unroll
  for (int mi = 0; mi < 8; ++mi) {
#pragma unroll
    for (int ni = 0; ni < 4; ++ni) {
      const int col  = bn + wc * 64 + ni * 16 + fr;
      const int row0 = bm + wr * 128 + mi * 16 + kq * 4;
      const f32x4 a = acc[mi][ni];
      if constexpr (MODE == 0) {
        float* O = (float*)out + (size_t)blockIdx.z * sO;
#pragma unroll
        for (int j = 0; j < 4; ++j) O[(size_t)(row0 + j) * ldo + col] = a[j];
      } else if constexpr (MODE == 1) {
        _Float16* O = (_Float16*)out;
        const float bb = bias[col];
#pragma unroll
        for (int j = 0; j < 4; ++j)
          O[(size_t)(row0 + j) * ldo + col] = (_Float16)(a[j] + bb);
      } else if constexpr (MODE == 2) {
        _Float16* O = (_Float16*)out;
        const float bb = bias[col];
        half4 h;
#pragma unroll
        for (int j = 0; j < 4; ++j) h[j] = (_Float16)(a[j] + bb);
        *(half4*)(O + (size_t)col * ldo + row0) = h;
      } else {  // MODE 3: fp16 row-major, no bias (scores)
        _Float16* O = (_Float16*)out + (size_t)blockIdx.z * sO;
#pragma unroll
        for (int j = 0; j < 4; ++j)
          O[(size_t)(row0 + j) * ldo + col] = (_Float16)a[j];
      }
    }
  }
}

__device__ __forceinline__ float wave_max_f(float v) {
#pragma unroll
  for (int o = 32; o; o >>= 1) v = fmaxf(v, __shfl_xor(v, o));
  return v;
}
__device__ __forceinline__ float wave_sum_f(float v) {
#pragma unroll
  for (int o = 32; o; o >>= 1) v += __shfl_xor(v, o);
  return v;
}

// one 256-thread block per row of 4096 fp16 scores -> fp16 probabilities
__global__ __launch_bounds__(256) void softmax_rows(
    const _Float16* __restrict__ S, _Float16* __restrict__ P)
{
  __shared__ float rmax[4], rsum[4];
  const int tid = threadIdx.x;
  const _Float16* s = S + (size_t)blockIdx.x * 4096;
  _Float16*       p = P + (size_t)blockIdx.x * 4096;

  const half8 v0 = ((const half8*)s)[tid];
  const half8 v1 = ((const half8*)s)[tid + 256];
  float f[16];
#pragma unroll
  for (int j = 0; j < 8; ++j) { f[j] = (float)v0[j]; f[8 + j] = (float)v1[j]; }

  float m = f[0];
#pragma unroll
  for (int j = 1; j < 16; ++j) m = fmaxf(m, f[j]);
  m = wave_max_f(m);
  if ((tid & 63) == 0) rmax[tid >> 6] = m;
  __syncthreads();
  m = fmaxf(fmaxf(rmax[0], rmax[1]), fmaxf(rmax[2], rmax[3]));

  float sum = 0.f;
#pragma unroll
  for (int j = 0; j < 16; ++j) { f[j] = __expf(f[j] - m); sum += f[j]; }
  sum = wave_sum_f(sum);
  if ((tid & 63) == 0) rsum[tid >> 6] = sum;
  __syncthreads();
  sum = rsum[0] + rsum[1] + rsum[2] + rsum[3];
  const float inv = 1.0f / sum;

  half8 o0, o1;
#pragma unroll
  for (int j = 0; j < 8; ++j) {
    o0[j] = (_Float16)(f[j] * inv);
    o1[j] = (_Float16)(f[8 + j] * inv);
  }
  ((half8*)p)[tid] = o0;
  ((half8*)p)[tid + 256] = o1;
}

__global__ __launch_bounds__(256) void cvt_f32_f16(
    const float* __restrict__ in, _Float16* __restrict__ out, int n4)
{
  const int stride = gridDim.x * 256;
  for (int idx = blockIdx.x * 256 + threadIdx.x; idx < n4; idx += stride) {
    const f32x4 x = ((const f32x4*)in)[idx];
    half4 h;
#pragma unroll
    for (int j = 0; j < 4; ++j) h[j] = (_Float16)x[j];
    ((half4*)out)[idx] = h;
  }
}

extern "C" void kernel_launch(void* const* d_in, const int* in_sizes, int n_in,
                              void* d_out, int out_size, void* d_ws, size_t ws_size,
                              hipStream_t stream)
{
  const float* X  = (const float*)d_in[0];
  const float* Wq = (const float*)d_in[1];
  const float* bq = (const float*)d_in[2];
  const float* Wk = (const float*)d_in[3];
  const float* bk = (const float*)d_in[4];
  const float* Wv = (const float*)d_in[5];
  const float* bv = (const float*)d_in[6];
  float* out = (float*)d_out;

  const size_t NX = (size_t)2 * 4096 * 2048;  // 16,777,216
  const size_t NW = (size_t)2048 * 2048;      //  4,194,304
  const size_t NS = (size_t)2 * 4096 * 4096;  // 33,554,432

  // Workspace layout (lifetime-aliased):
  //  [0 ..)         : Ssc fp16 (67MB) — earlier hosts Xh + W*h fp16 (dead by QK^T)
  //  [NS*4 ..)      : Q | Kp fp16 — later aliased by P fp16
  //  [NS*4+2*NX*2..): Vt fp16 [2048][8192]
  char* w = (char*)d_ws;
  _Float16* Ssc = (_Float16*)w;
  _Float16* Xh  = (_Float16*)w;
  _Float16* Wqh = (_Float16*)(w + NX * 2);
  _Float16* Wkh = (_Float16*)(w + NX * 2 + NW * 2);
  _Float16* Wvh = (_Float16*)(w + NX * 2 + 2 * NW * 2);
  _Float16* Q   = (_Float16*)(w + NS * 4);
  _Float16* Kp  = (_Float16*)(w + NS * 4 + NX * 2);
  _Float16* P   = (_Float16*)(w + NS * 4);            // aliases Q+Kp
  _Float16* Vt  = (_Float16*)(w + NS * 4 + 2 * NX * 2);

  // 1) fp32 -> fp16 conversions
  cvt_f32_f16<<<2048, 256, 0, stream>>>(X,  Xh,  (int)(NX / 4));
  cvt_f32_f16<<<512,  256, 0, stream>>>(Wq, Wqh, (int)(NW / 4));
  cvt_f32_f16<<<512,  256, 0, stream>>>(Wk, Wkh, (int)(NW / 4));
  cvt_f32_f16<<<512,  256, 0, stream>>>(Wv, Wvh, (int)(NW / 4));

  const dim3 blk(512);
  // 2) projections: [8192,2048] = Xh @ W^T + b
  gemm256<1><<<dim3(32, 8, 1), blk, 0, stream>>>(Xh, 2048, Wqh, 2048, bq,
                                                 Q, 2048, 2048, 0, 0, 0);
  gemm256<1><<<dim3(32, 8, 1), blk, 0, stream>>>(Xh, 2048, Wkh, 2048, bk,
                                                 Kp, 2048, 2048, 0, 0, 0);
  gemm256<2><<<dim3(32, 8, 1), blk, 0, stream>>>(Xh, 2048, Wvh, 2048, bv,
                                                 Vt, 8192, 2048, 0, 0, 0);
  // 3) scores: per batch, S = Q K^T (fp16 out)
  gemm256<3><<<dim3(16, 16, 2), blk, 0, stream>>>(
      Q, 2048, Kp, 2048, nullptr, Ssc, 4096, 2048,
      (size_t)4096 * 2048, (size_t)4096 * 2048, (size_t)4096 * 4096);
  // 4) row softmax (fp16 in) -> fp16 probs
  softmax_rows<<<8192, 256, 0, stream>>>(Ssc, P);
  // 5) out: per batch, [4096,2048] = P @ Vt^T
  gemm256<0><<<dim3(16, 8, 2), blk, 0, stream>>>(
      P, 4096, Vt, 8192, nullptr, out, 2048, 4096,
      (size_t)4096 * 4096, (size_t)4096, (size_t)4096 * 2048);
}